// Round 2
// baseline (482.991 us; speedup 1.0000x reference)
//
#include <hip/hip_runtime.h>
#include <stdint.h>

typedef uint32_t u32;
typedef uint64_t u64;

#define HWD 512
#define NTX 64            // 64x64 grid of 8x8 tiles
#define NTILES 4096
#define SORT_B 256        // radix sort blocks
#define TB2 64            // tile-binning hist blocks

// exp(-r2/2) for r2 = dx*dx+dy*dy in {0,1,2,4,5,8}
__constant__ float WTAB[9] = {1.0f, 0.60653065971f, 0.36787944117f, 0.0f,
                              0.13533528324f, 0.08208499862f, 0.0f, 0.0f, 0.01831563889f};

// ---------------- pose inverse (exact for the given unitriangular pose) ----------------
__global__ void inv4_kernel(const float* __restrict__ pose, float* __restrict__ pinv,
                            u32* __restrict__ flag){
  *flag = 0u;
  double a[4][8];
  for (int i=0;i<4;i++) for (int j=0;j<4;j++){ a[i][j]=(double)pose[i*4+j]; a[i][4+j]=(i==j)?1.0:0.0; }
  for (int c=0;c<4;c++){
    int p=c; double best=fabs(a[c][c]);
    for (int r=c+1;r<4;r++){ double v=fabs(a[r][c]); if (v>best){best=v;p=r;} }
    if (p!=c) for (int j=0;j<8;j++){ double tt=a[c][j]; a[c][j]=a[p][j]; a[p][j]=tt; }
    double inv=1.0/a[c][c];
    for (int j=0;j<8;j++) a[c][j]*=inv;
    for (int r=0;r<4;r++) if (r!=c){ double f=a[r][c]; for (int j=0;j<8;j++) a[r][j]-=f*a[c][j]; }
  }
  for (int i=0;i<4;i++) for (int j=0;j<4;j++) pinv[i*4+j]=(float)a[i][4+j];
}

// ---------------- mask dtype probe (u8 bool vs i32 vs f32) ----------------
// Scans first N/4 32-bit words (safe under all candidate widths).
// i32 bool data: every word is 0 or 1 (upper 3 bytes never set).
// u8 bool data (mask of ones): words look like 0x01010101 -> upper bytes set.
// f32 data: words are 0x3F800000 (1.0f) or 0.
__global__ void maskprobe_kernel(const u32* __restrict__ mw, u32* __restrict__ flag, int nwords){
  int i = blockIdx.x*256 + threadIdx.x;
  if (i>=nwords) return;
  u32 w = mw[i];
  if (w == 0x3F800000u) atomicOr(flag, 2u);
  else if ((w & 0xFFFFFF00u) != 0u) atomicOr(flag, 1u);
}

// ---------------- per-gaussian projection / shading / sort keys ----------------
__global__ void prep_kernel(const float* __restrict__ means, const float* __restrict__ sh,
    const float* __restrict__ opac, const void* __restrict__ maskp,
    const float* __restrict__ pinv, const u32* __restrict__ flag,
    u32* __restrict__ keys, u32* __restrict__ idx,
    u32* __restrict__ xy, float4* __restrict__ acol, int N){
  int i = blockIdx.x*256 + threadIdx.x;
  if (i>=N) return;
  u32 f = *flag;
  bool mk;
  if (f & 1u)      mk = (((const unsigned char*)maskp)[i] != 0);
  else if (f & 2u) mk = (((const float*)maskp)[i] != 0.0f);
  else             mk = (((const int*)maskp)[i] != 0);
  float x=means[3*i], y=means[3*i+1], z=means[3*i+2];
  float cx = pinv[0]*x + pinv[1]*y + pinv[2]*z + pinv[3];
  float cy = pinv[4]*x + pinv[5]*y + pinv[6]*z + pinv[7];
  float cz = pinv[8]*x + pinv[9]*y + pinv[10]*z + pinv[11];
  // exact op order of the reference: ((c*FX)/z) + CX, each fp32-rounded
  float x2d = (cx*409.6f)/cz; x2d = x2d + 256.0f;
  float y2d = (cy*409.6f)/cz; y2d = y2d + 256.0f;
  // trunc(x2d) in [0,511]  <=>  x2d in (-1, 512)
  bool okx = (x2d > -1.0f) && (x2d < 512.0f);
  bool oky = (y2d > -1.0f) && (y2d < 512.0f);
  bool valid = mk && okx && oky;
  int xi = (int)x2d, yi = (int)y2d;
  float alpha = valid ? opac[i] : 0.0f;
  u32 pk = valid ? ((u32)xi | ((u32)yi<<16)) : 0xFFFFFFFFu;
  float c0 = 1.0f/(1.0f+expf(-sh[48*i]));
  float c1 = 1.0f/(1.0f+expf(-sh[48*i+16]));
  float c2 = 1.0f/(1.0f+expf(-sh[48*i+32]));
  // order-preserving float->uint, then invert for descending-z ascending-key sort
  u32 u = __float_as_uint(cz);
  u32 ou = u ^ (((u>>31)!=0u) ? 0xFFFFFFFFu : 0x80000000u);
  keys[i] = ~ou;
  idx[i]  = (u32)i;
  xy[i]   = pk;
  acol[i] = make_float4(alpha, c0, c1, c2);
}

// ---------------- stable LSD radix sort (8-bit digits) ----------------
__global__ void rhist_kernel(const u32* __restrict__ keys, u32* __restrict__ hist,
                             int shift, int N, int ipb){
  __shared__ u32 h[256];
  int t=threadIdx.x, blk=blockIdx.x;
  h[t]=0u; __syncthreads();
  int base = blk*ipb;
  for (int k=0;k<ipb;k+=256){
    int i = base + k + t;
    if (i<N) atomicAdd(&h[(keys[i]>>shift)&255u],1u);
  }
  __syncthreads();
  hist[t*SORT_B + blk] = h[t];
}

__global__ void rscan_kernel(u32* __restrict__ hist){
  __shared__ u32 s[256];
  int t=threadIdx.x;
  u32 sum=0;
  for (int j=0;j<256;j++) sum += hist[t*256+j];
  s[t]=sum; __syncthreads();
  for (int off=1;off<256;off<<=1){ u32 v=(t>=off)?s[t-off]:0u; __syncthreads(); s[t]+=v; __syncthreads(); }
  u32 run = (t==0)?0u:s[t-1];
  for (int j=0;j<256;j++){ u32 tmp=hist[t*256+j]; hist[t*256+j]=run; run+=tmp; }
}

__global__ void __launch_bounds__(64) rscatter_kernel(const u32* __restrict__ kin, const u32* __restrict__ iin,
    u32* __restrict__ kout, u32* __restrict__ iout, const u32* __restrict__ hist,
    int shift, int N, int ipb){
  __shared__ u32 bbase[256];
  int t=threadIdx.x, blk=blockIdx.x;
  for (int d=t; d<256; d+=64) bbase[d]=hist[d*SORT_B+blk];
  __syncthreads();
  int base=blk*ipb;
  for (int k=0;k<ipb;k+=64){
    int i=base+k+t;
    bool live=(i<N);
    u32 key = live? kin[i]:0u;
    u32 pay = live? iin[i]:0u;
    u32 d = (key>>shift)&255u;
    u64 m=~0ull;
    #pragma unroll
    for (int b=0;b<8;b++){ u64 bal=__ballot((int)((d>>b)&1u)); m &= ((d>>b)&1u)? bal : ~bal; }
    m &= __ballot((int)live);
    u64 lt=(1ull<<t)-1ull;
    int rank=__popcll(m&lt);
    if (live){
      u32 pos = bbase[d]+(u32)rank;
      kout[pos]=key; iout[pos]=pay;
      if (rank==0) atomicAdd(&bbase[d], (u32)__popcll(m));
    }
    __syncthreads();
  }
}

// ---------------- gather into sorted order ----------------
__global__ void reorder_kernel(const u32* __restrict__ sidx, const u32* __restrict__ xy,
    const float4* __restrict__ acol, u32* __restrict__ rxy, float4* __restrict__ racol, int N){
  int p=blockIdx.x*256+threadIdx.x; if (p>=N) return;
  u32 g=sidx[p]; rxy[p]=xy[g]; racol[p]=acol[g];
}

// ---------------- tile binning (8x8 tiles) ----------------
__device__ __forceinline__ void tile_range(u32 pk, int& tx0,int& tx1,int& ty0,int& ty1, bool& val){
  val = (pk!=0xFFFFFFFFu);
  int xi = (int)(pk&0xFFFFu), yi=(int)(pk>>16);
  int x0 = xi-2; if (x0<0) x0=0;
  int x1 = xi+2; if (x1>HWD-1) x1=HWD-1;
  int y0 = yi-2; if (y0<0) y0=0;
  int y1 = yi+2; if (y1>HWD-1) y1=HWD-1;
  tx0=x0>>3; tx1=x1>>3; ty0=y0>>3; ty1=y1>>3;
}

__global__ void ctiles_kernel(const u32* __restrict__ rxy, u32* __restrict__ ct, int N){
  int p=blockIdx.x*256+threadIdx.x; if (p>=N) return;
  bool val; int tx0,tx1,ty0,ty1; tile_range(rxy[p],tx0,tx1,ty0,ty1,val);
  ct[p] = val? (u32)((tx1-tx0+1)*(ty1-ty0+1)) : 0u;
}

// generic 3-kernel exclusive scan (len <= 256*1024)
__global__ void scan1_kernel(const u32* __restrict__ in, u32* __restrict__ out,
                             u32* __restrict__ bsum, int len){
  __shared__ u32 s[256];
  int t=threadIdx.x, blk=blockIdx.x;
  int base=blk*1024 + t*4;
  u32 v0=(base+0<len)?in[base+0]:0u;
  u32 v1=(base+1<len)?in[base+1]:0u;
  u32 v2=(base+2<len)?in[base+2]:0u;
  u32 v3=(base+3<len)?in[base+3]:0u;
  s[t]=v0+v1+v2+v3; __syncthreads();
  for (int off=1;off<256;off<<=1){ u32 x=(t>=off)?s[t-off]:0u; __syncthreads(); s[t]+=x; __syncthreads(); }
  if (t==0) bsum[blk]=s[255];
  u32 run=(t==0)?0u:s[t-1];
  if (base+0<len) out[base+0]=run; run+=v0;
  if (base+1<len) out[base+1]=run; run+=v1;
  if (base+2<len) out[base+2]=run; run+=v2;
  if (base+3<len) out[base+3]=run;
}

__global__ void scan2_kernel(u32* __restrict__ bsum, u32* __restrict__ Mout, int len){
  __shared__ u32 s[256];
  int t=threadIdx.x;
  s[t]=(t<len)?bsum[t]:0u; __syncthreads();
  for (int off=1;off<256;off<<=1){ u32 x=(t>=off)?s[t-off]:0u; __syncthreads(); s[t]+=x; __syncthreads(); }
  if (t==0 && Mout) *Mout=s[255];
  if (t<len) bsum[t]=(t==0)?0u:s[t-1];
}

__global__ void scan3_kernel(u32* __restrict__ out, const u32* __restrict__ bsum, int len){
  int t=threadIdx.x, blk=blockIdx.x;
  int base=blk*1024 + t*4;
  u32 b=bsum[blk];
  if (base+0<len) out[base+0]+=b;
  if (base+1<len) out[base+1]+=b;
  if (base+2<len) out[base+2]+=b;
  if (base+3<len) out[base+3]+=b;
}

__global__ void emit_kernel(const u32* __restrict__ rxy, const u32* __restrict__ offs,
                            u32* __restrict__ entries, int N){
  int p=blockIdx.x*256+threadIdx.x; if (p>=N) return;
  bool val; int tx0,tx1,ty0,ty1; tile_range(rxy[p],tx0,tx1,ty0,ty1,val);
  if (!val) return;
  u32 o=offs[p];
  for (int ty=ty0; ty<=ty1; ty++)
    for (int tx=tx0; tx<=tx1; tx++)
      entries[o++] = ((u32)(ty*NTX+tx)<<18) | (u32)p;
}

__global__ void thist_kernel(const u32* __restrict__ entries, const u32* __restrict__ Mptr,
                             u32* __restrict__ th, int ipb){
  __shared__ u32 h[4096];
  int t=threadIdx.x, blk=blockIdx.x;
  for (int d=t; d<4096; d+=256) h[d]=0u;
  __syncthreads();
  u32 M=*Mptr;
  int base=blk*ipb;
  for (int k=0;k<ipb;k+=256){
    u32 i=(u32)(base+k+t);
    if (i<M) atomicAdd(&h[entries[i]>>18],1u);
  }
  __syncthreads();
  for (int d=t; d<4096; d+=256) th[d*TB2+blk]=h[d];
}

__global__ void __launch_bounds__(64) tscatter_kernel(const u32* __restrict__ entries, const u32* __restrict__ Mptr,
    u32* __restrict__ sout, const u32* __restrict__ thS, int ipb){
  __shared__ u32 bbase[4096];
  int t=threadIdx.x, blk=blockIdx.x;
  for (int d=t; d<4096; d+=64) bbase[d]=thS[d*TB2+blk];
  __syncthreads();
  u32 M=*Mptr;
  int base=blk*ipb;
  for (int k=0;k<ipb;k+=64){
    u32 i=(u32)(base+k+t);
    bool live=(i<M);
    u32 e= live? entries[i]:0u;
    u32 d=e>>18;
    u64 m=~0ull;
    #pragma unroll
    for (int b=0;b<12;b++){ u64 bal=__ballot((int)((d>>b)&1u)); m &= ((d>>b)&1u)?bal:~bal; }
    m &= __ballot((int)live);
    u64 lt=(1ull<<t)-1ull;
    int rank=__popcll(m&lt);
    if (live){
      sout[bbase[d]+(u32)rank]=e;
      if (rank==0) atomicAdd(&bbase[d],(u32)__popcll(m));
    }
    __syncthreads();
  }
}

// ---------------- render: 8 waves/tile, affine segment composition ----------------
__global__ void __launch_bounds__(512) render_kernel(const u32* __restrict__ sortedE, const u32* __restrict__ rxy,
    const float4* __restrict__ racol, const u32* __restrict__ thS, const u32* __restrict__ Mptr,
    float* __restrict__ out){
  __shared__ u32   sxy[8][64];
  __shared__ float4 sac[8][64];
  __shared__ float4 comb[8][64];
  int tile=blockIdx.x;
  int t=threadIdx.x, w=t>>6, lane=t&63;
  int px=(tile&(NTX-1))*8 + (lane&7), py=(tile/NTX)*8 + (lane>>3);
  u32 start=thS[tile*TB2];
  u32 end = (tile<NTILES-1)? thS[(tile+1)*TB2] : *Mptr;
  int len = (int)(end-start);
  int s0=(int)start + (len*w)/8;
  int s1=(int)start + (len*(w+1))/8;
  float T=1.0f, cr=0.0f, cg=0.0f, cb=0.0f;
  for (int base=s0; base<s1; base+=64){
    int i=base+lane;
    if (i<s1){
      u32 e=sortedE[i];
      u32 p=e & 0x3FFFFu;
      sxy[w][lane]=rxy[p];
      sac[w][lane]=racol[p];
    }
    __builtin_amdgcn_wave_barrier();
    int cnt=min(64, s1-base);
    for (int j=0;j<cnt;j++){
      u32 exy=sxy[w][j];
      int dx=px-(int)(exy&0xFFFFu);
      int dy=py-(int)(exy>>16);
      if ((unsigned)(dx+2)<=4u && (unsigned)(dy+2)<=4u){
        float4 ac=sac[w][j];
        float aw=ac.x*WTAB[dx*dx+dy*dy];
        float om=1.0f-aw;
        T*=om;
        cr=om*cr+aw*ac.y;
        cg=om*cg+aw*ac.z;
        cb=om*cb+aw*ac.w;
      }
    }
    __builtin_amdgcn_wave_barrier();
  }
  comb[w][lane]=make_float4(T,cr,cg,cb);
  __syncthreads();
  if (w==0){
    float r=0.0f,g=0.0f,b=0.0f;
    #pragma unroll
    for (int s=0;s<8;s++){
      float4 c=comb[s][lane];
      r=c.x*r+c.y; g=c.x*g+c.z; b=c.x*b+c.w;
    }
    int o=py*HWD+px;
    out[o]=r; out[HWD*HWD+o]=g; out[2*HWD*HWD+o]=b;
  }
}

// ---------------- launcher ----------------
extern "C" void kernel_launch(void* const* d_in, const int* in_sizes, int n_in,
                              void* d_out, int out_size, void* d_ws, size_t ws_size,
                              hipStream_t stream){
  const float* pose=(const float*)d_in[0];
  const float* means=(const float*)d_in[1];
  const float* sh=(const float*)d_in[2];
  const float* opac=(const float*)d_in[3];
  const void* mask=(const void*)d_in[4];
  int N=in_sizes[4];
  if (N<=0) return;
  char* ws=(char*)d_ws;
  size_t off=0;
  auto alloc=[&](size_t bytes)->void*{ void* p=(void*)(ws+off); off=(off+bytes+255)&~(size_t)255; return p; };
  float* pinv =(float*)alloc(64);
  u32* flag   =(u32*)alloc(4);
  u32* keysA  =(u32*)alloc(4ull*N);
  u32* keysB  =(u32*)alloc(4ull*N);
  u32* idxA   =(u32*)alloc(4ull*N);
  u32* idxB   =(u32*)alloc(4ull*N);
  u32* rh     =(u32*)alloc(4ull*256*SORT_B);
  u32* xy     =(u32*)alloc(4ull*N);
  float4* acol=(float4*)alloc(16ull*N);
  u32* rxy    =(u32*)alloc(4ull*N);
  float4* racol=(float4*)alloc(16ull*N);
  u32* ct     =(u32*)alloc(4ull*N);
  u32* offs   =(u32*)alloc(4ull*N);
  u32* bsum   =(u32*)alloc(1024);
  u32* Mptr   =(u32*)alloc(4);
  u32* entries=(u32*)alloc(16ull*N);   // <=4 tiles per gaussian
  u32* sentries=(u32*)alloc(16ull*N);
  u32* th     =(u32*)alloc(4ull*4096*TB2);
  u32* thS    =(u32*)alloc(4ull*4096*TB2);
  (void)n_in; (void)out_size; (void)ws_size;

  int nb=(N+255)/256;
  inv4_kernel<<<1,1,0,stream>>>(pose,pinv,flag);
  int nwords=N/4;
  maskprobe_kernel<<<(nwords+255)/256,256,0,stream>>>((const u32*)mask,flag,nwords);
  prep_kernel<<<nb,256,0,stream>>>(means,sh,opac,mask,pinv,flag,keysA,idxA,xy,acol,N);

  int perb=(((N+SORT_B-1)/SORT_B)+255)/256*256;  // items per block, mult of 256
  for (int p=0;p<4;p++){
    const u32 *ki=(p&1)?keysB:keysA, *ii=(p&1)?idxB:idxA;
    u32 *ko=(p&1)?keysA:keysB, *io=(p&1)?idxA:idxB;
    rhist_kernel<<<SORT_B,256,0,stream>>>(ki,rh,8*p,N,perb);
    rscan_kernel<<<1,256,0,stream>>>(rh);
    rscatter_kernel<<<SORT_B,64,0,stream>>>(ki,ii,ko,io,rh,8*p,N,perb);
  }
  reorder_kernel<<<nb,256,0,stream>>>(idxA,xy,acol,rxy,racol,N);

  ctiles_kernel<<<nb,256,0,stream>>>(rxy,ct,N);
  int sblocks=(N+1023)/1024;
  scan1_kernel<<<sblocks,256,0,stream>>>(ct,offs,bsum,N);
  scan2_kernel<<<1,256,0,stream>>>(bsum,Mptr,sblocks);
  scan3_kernel<<<sblocks,256,0,stream>>>(offs,bsum,N);
  emit_kernel<<<nb,256,0,stream>>>(rxy,offs,entries,N);

  int ipb2=(((4*N+TB2-1)/TB2)+255)/256*256;
  thist_kernel<<<TB2,256,0,stream>>>(entries,Mptr,th,ipb2);
  int hlen=4096*TB2;
  int sblocks2=(hlen+1023)/1024;
  scan1_kernel<<<sblocks2,256,0,stream>>>(th,thS,bsum,hlen);
  scan2_kernel<<<1,256,0,stream>>>(bsum,Mptr,sblocks2);   // rewrites same M (sum of hist == M)
  scan3_kernel<<<sblocks2,256,0,stream>>>(thS,bsum,hlen);
  tscatter_kernel<<<TB2,64,0,stream>>>(entries,Mptr,sentries,thS,ipb2);

  render_kernel<<<NTILES,512,0,stream>>>(sentries,rxy,racol,thS,Mptr,(float*)d_out);
}

// Round 3
// 376.417 us; speedup vs baseline: 1.2831x; 1.2831x over previous
//
#include <hip/hip_runtime.h>
#include <stdint.h>

typedef uint32_t u32;
typedef uint64_t u64;

#define HWD 512
#define NTX 64            // 64x64 grid of 8x8 tiles
#define NTILES 4096

// ---------------- prep: pose-inverse + mask-probe + project/shade + pass0 hist ----------------
__global__ void __launch_bounds__(256) prep_kernel(const float* __restrict__ pose,
    const float* __restrict__ means, const float* __restrict__ sh,
    const float* __restrict__ opac, const u32* __restrict__ maskw,
    u32* __restrict__ keys, u32* __restrict__ xy, float4* __restrict__ acol,
    u32* __restrict__ h0, int N, int SB){
  __shared__ float pinvS[12];
  __shared__ u32 hh[256];
  __shared__ u32 mflag;
  int t=threadIdx.x, blk=blockIdx.x;
  int i=blk*256+t;
  hh[t]=0u;
  if (t<64){
    // mask dtype probe on first 64 words (uniform across blocks -> uniform decision)
    u32 w=maskw[t];
    bool isf=(w==0x3F800000u);
    bool ishi=((w&0xFFFFFF00u)!=0u)&&!isf;
    u64 bf=__ballot((int)isf), bh=__ballot((int)ishi);
    if (t==0) mflag = bh? 1u : (bf? 2u : 0u);   // 1=u8, 2=f32, 0=i32
  }
  if (t==0){
    double a[4][8];
    for(int r=0;r<4;r++)for(int c=0;c<4;c++){a[r][c]=(double)pose[r*4+c];a[r][4+c]=(r==c)?1.0:0.0;}
    for(int c=0;c<4;c++){
      int p=c;double best=fabs(a[c][c]);
      for(int r=c+1;r<4;r++){double v=fabs(a[r][c]);if(v>best){best=v;p=r;}}
      if(p!=c)for(int j=0;j<8;j++){double tt=a[c][j];a[c][j]=a[p][j];a[p][j]=tt;}
      double inv=1.0/a[c][c];
      for(int j=0;j<8;j++)a[c][j]*=inv;
      for(int r=0;r<4;r++)if(r!=c){double f=a[r][c];for(int j=0;j<8;j++)a[r][j]-=f*a[c][j];}
    }
    for(int r=0;r<3;r++)for(int c=0;c<4;c++) pinvS[r*4+c]=(float)a[r][4+c];
  }
  __syncthreads();
  if (i<N){
    u32 f=mflag;
    bool mk;
    if (f==1u)      mk=(((const unsigned char*)maskw)[i]!=0);
    else if (f==2u) mk=(((const float*)maskw)[i]!=0.0f);
    else            mk=(((const int*)maskw)[i]!=0);
    float x=means[3*i], y=means[3*i+1], z=means[3*i+2];
    float cx=pinvS[0]*x+pinvS[1]*y+pinvS[2]*z+pinvS[3];
    float cy=pinvS[4]*x+pinvS[5]*y+pinvS[6]*z+pinvS[7];
    float cz=pinvS[8]*x+pinvS[9]*y+pinvS[10]*z+pinvS[11];
    // exact op order of the reference: ((c*FX)/z) + CX, each fp32-rounded
    float x2d=(cx*409.6f)/cz; x2d=x2d+256.0f;
    float y2d=(cy*409.6f)/cz; y2d=y2d+256.0f;
    bool okx=(x2d>-1.0f)&&(x2d<512.0f);
    bool oky=(y2d>-1.0f)&&(y2d<512.0f);
    bool valid=mk&&okx&&oky;
    int xi=(int)x2d, yi=(int)y2d;
    float alpha= valid? opac[i]:0.0f;
    u32 pk= valid? ((u32)xi|((u32)yi<<16)) : 0xFFFFFFFFu;
    float c0=1.0f/(1.0f+expf(-sh[48*i]));
    float c1=1.0f/(1.0f+expf(-sh[48*i+16]));
    float c2=1.0f/(1.0f+expf(-sh[48*i+32]));
    u32 u=__float_as_uint(cz);
    u32 ou=u^(((u>>31)!=0u)?0xFFFFFFFFu:0x80000000u);
    u32 key=~ou;                    // ascending key == descending z
    keys[i]=key;
    xy[i]=pk;
    acol[i]=make_float4(alpha,c0,c1,c2);
    atomicAdd(&hh[key&255u],1u);
  }
  __syncthreads();
  h0[t*SB+blk]=hh[t];
}

// ---------------- generic scan: scan1 (block scan + block sums), scanfix (redundant prefix) ----------------
__global__ void __launch_bounds__(256) scan1_kernel(const u32* __restrict__ in, u32* __restrict__ out,
                             u32* __restrict__ bsum, int len){
  __shared__ u32 s[256];
  int t=threadIdx.x, blk=blockIdx.x;
  int base=blk*1024 + t*4;
  u32 v0=(base+0<len)?in[base+0]:0u;
  u32 v1=(base+1<len)?in[base+1]:0u;
  u32 v2=(base+2<len)?in[base+2]:0u;
  u32 v3=(base+3<len)?in[base+3]:0u;
  s[t]=v0+v1+v2+v3; __syncthreads();
  for (int off=1;off<256;off<<=1){ u32 x=(t>=off)?s[t-off]:0u; __syncthreads(); s[t]+=x; __syncthreads(); }
  if (t==255) bsum[blk]=s[255];
  u32 run=(t==0)?0u:s[t-1];
  if (base+0<len) out[base+0]=run; run+=v0;
  if (base+1<len) out[base+1]=run; run+=v1;
  if (base+2<len) out[base+2]=run; run+=v2;
  if (base+3<len) out[base+3]=run;
}

__global__ void __launch_bounds__(256) scanfix_kernel(u32* __restrict__ out, const u32* __restrict__ bsum,
                               u32* __restrict__ Mout, int nblk, int len){
  __shared__ u32 red[256];
  int t=threadIdx.x, blk=blockIdx.x;
  u32 s=0u;
  for (int j=t;j<blk;j+=256) s+=bsum[j];
  red[t]=s; __syncthreads();
  for (int off=128;off>0;off>>=1){ if(t<off) red[t]+=red[t+off]; __syncthreads(); }
  u32 base=red[0];
  if (Mout && blk==nblk-1 && t==0) *Mout = base + bsum[blk];
  int i0=blk*1024+t*4;
  #pragma unroll
  for (int k=0;k<4;k++) if (i0+k<len) out[i0+k]+=base;
}

// ---------------- radix scatter passes (stable, 1 wave/block, 256 items/block) ----------------
__global__ void __launch_bounds__(64) rscatter_kernel(const u32* __restrict__ kin,
    const u32* __restrict__ iin, u32* __restrict__ kout, u32* __restrict__ iout,
    const u32* __restrict__ histS, u32* __restrict__ hnext,
    int shift, int nshift, int N, int SB, int pass0){
  __shared__ u32 bbase[256];
  int t=threadIdx.x, blk=blockIdx.x;
  #pragma unroll
  for (int d=t; d<256; d+=64) bbase[d]=histS[d*SB+blk];
  int base=blk*256;
  #pragma unroll
  for (int c=0;c<4;c++){
    int i=base+c*64+t;
    bool live=(i<N);
    u32 key=live?kin[i]:0u;
    u32 pay= pass0? (u32)i : (live?iin[i]:0u);
    u32 d=(key>>shift)&255u;
    u64 m=~0ull;
    #pragma unroll
    for (int b=0;b<8;b++){ u64 bal=__ballot((int)((d>>b)&1u)); m&=((d>>b)&1u)?bal:~bal; }
    m&=__ballot((int)live);
    int rank=__popcll(m&((1ull<<t)-1ull));
    if (live){
      u32 pos=bbase[d]+(u32)rank;
      kout[pos]=key; iout[pos]=pay;
      if (hnext) atomicAdd(&hnext[((key>>nshift)&255u)*SB+(pos>>8)],1u);
      if (rank==0) atomicAdd(&bbase[d],(u32)__popcll(m));
    }
  }
}

// final pass: fuse reorder (gather xy/acol into sorted order) + per-item tile-count
__global__ void __launch_bounds__(64) rscatter_final_kernel(const u32* __restrict__ kin,
    const u32* __restrict__ iin, const u32* __restrict__ xy, const float4* __restrict__ acol,
    u32* __restrict__ rxy, float4* __restrict__ racol, u32* __restrict__ ct,
    const u32* __restrict__ histS, int shift, int N, int SB){
  __shared__ u32 bbase[256];
  int t=threadIdx.x, blk=blockIdx.x;
  #pragma unroll
  for (int d=t; d<256; d+=64) bbase[d]=histS[d*SB+blk];
  int base=blk*256;
  #pragma unroll
  for (int c=0;c<4;c++){
    int i=base+c*64+t;
    bool live=(i<N);
    u32 key=live?kin[i]:0u;
    u32 d=(key>>shift)&255u;
    u64 m=~0ull;
    #pragma unroll
    for (int b=0;b<8;b++){ u64 bal=__ballot((int)((d>>b)&1u)); m&=((d>>b)&1u)?bal:~bal; }
    m&=__ballot((int)live);
    int rank=__popcll(m&((1ull<<t)-1ull));
    if (live){
      u32 pos=bbase[d]+(u32)rank;
      u32 g=iin[i];
      u32 pk=xy[g];
      rxy[pos]=pk;
      racol[pos]=acol[g];
      u32 cnt=0u;
      if (pk!=0xFFFFFFFFu){
        int xi=(int)(pk&0xFFFFu), yi=(int)(pk>>16);
        int tx0=max(xi-2,0)>>3, tx1=min(xi+2,HWD-1)>>3;
        int ty0=max(yi-2,0)>>3, ty1=min(yi+2,HWD-1)>>3;
        cnt=(u32)((tx1-tx0+1)*(ty1-ty0+1));
      }
      ct[pos]=cnt;
      if (rank==0) atomicAdd(&bbase[d],(u32)__popcll(m));
    }
  }
}

// ---------------- emit entries (+ fused tile histogram via global atomics) ----------------
__global__ void __launch_bounds__(256) emit_kernel(const u32* __restrict__ rxy,
    const u32* __restrict__ coffs, u32* __restrict__ entries, u32* __restrict__ th,
    int N, int TBv, u32 ipb2){
  int p=blockIdx.x*256+threadIdx.x; if(p>=N) return;
  u32 pk=rxy[p]; if(pk==0xFFFFFFFFu) return;
  int xi=(int)(pk&0xFFFFu), yi=(int)(pk>>16);
  int tx0=max(xi-2,0)>>3, tx1=min(xi+2,HWD-1)>>3;
  int ty0=max(yi-2,0)>>3, ty1=min(yi+2,HWD-1)>>3;
  u32 o=coffs[p];
  for (int ty=ty0;ty<=ty1;ty++)
    for (int tx=tx0;tx<=tx1;tx++){
      u32 tile=(u32)(ty*NTX+tx);
      entries[o]=(tile<<18)|(u32)p;
      atomicAdd(&th[tile*(u32)TBv + (o/ipb2)],1u);
      o++;
    }
}

// ---------------- stable tile scatter (1 wave/block, prefetched chunks) ----------------
__global__ void __launch_bounds__(64) tscatter_kernel(const u32* __restrict__ entries,
    const u32* __restrict__ Mptr, u32* __restrict__ sout, const u32* __restrict__ thS,
    int TBv, u32 ipb2){
  __shared__ u32 bbase[4096];
  int t=threadIdx.x, blk=blockIdx.x;
  for (int d=t; d<4096; d+=64) bbase[d]=thS[d*TBv+blk];
  u32 M=*Mptr;
  u32 base=(u32)blk*ipb2;
  int nch=(int)(ipb2>>6);
  u32 i0=base+(u32)t;
  u32 eCur=(i0<M)?entries[i0]:0xFFFFFFFFu;
  for (int c=0;c<nch;c++){
    u32 inext=base+(u32)(c+1)*64u+(u32)t;
    u32 eNext=((c+1)<nch && inext<M)? entries[inext]:0xFFFFFFFFu;
    bool live=(eCur!=0xFFFFFFFFu);
    if (__ballot((int)live)!=0ull){
      u32 d=eCur>>18;
      u64 m=~0ull;
      #pragma unroll
      for (int b=0;b<12;b++){ u64 bal=__ballot((int)((d>>b)&1u)); m&=((d>>b)&1u)?bal:~bal; }
      m&=__ballot((int)live);
      int rank=__popcll(m&((1ull<<t)-1ull));
      if (live){
        u32 pos=bbase[d]+(u32)rank;
        sout[pos]=eCur;
        if (rank==0) atomicAdd(&bbase[d],(u32)__popcll(m));
      }
    }
    eCur=eNext;
  }
}

// ---------------- render: 8 waves/tile, affine segment composition, reg-chunked LDS ----------------
__global__ void __launch_bounds__(512) render_kernel(const u32* __restrict__ sortedE,
    const u32* __restrict__ rxy, const float4* __restrict__ racol,
    const u32* __restrict__ thS, const u32* __restrict__ Mptr,
    float* __restrict__ out, int TBv){
  __shared__ u32    sxy[8][64];
  __shared__ float4 sac[8][64];
  __shared__ float4 comb[8][64];
  int tile=blockIdx.x;
  int t=threadIdx.x, w=t>>6, lane=t&63;
  int px=(tile&(NTX-1))*8 + (lane&7), py=(tile/NTX)*8 + (lane>>3);
  u32 start=thS[tile*TBv];
  u32 end = (tile<NTILES-1)? thS[(tile+1)*TBv] : *Mptr;
  int len=(int)(end-start);
  int s0=(int)start + (len*w)/8;
  int s1=(int)start + (len*(w+1))/8;
  float T=1.0f, cr=0.0f, cg=0.0f, cb=0.0f;
  for (int base=s0; base<s1; base+=64){
    int i=base+lane;
    if (i<s1){
      u32 e=sortedE[i]; u32 p=e&0x3FFFFu;
      sxy[w][lane]=rxy[p];
      sac[w][lane]=racol[p];
    }
    __builtin_amdgcn_wave_barrier();
    int cnt=min(64, s1-base);
    int j=0;
    for (; j+8<=cnt; j+=8){
      u32 exy[8]; float4 ac[8];
      #pragma unroll
      for (int k=0;k<8;k++){ exy[k]=sxy[w][j+k]; ac[k]=sac[w][j+k]; }
      #pragma unroll
      for (int k=0;k<8;k++){
        int dx=px-(int)(exy[k]&0xFFFFu);
        int dy=py-(int)(exy[k]>>16);
        int r2=dx*dx+dy*dy;
        float aw=ac[k].x*exp2f(-0.72134752f*(float)r2);
        aw=(r2<=8)?aw:0.0f;
        float om=1.0f-aw;
        T*=om;
        cr=om*cr+aw*ac[k].y;
        cg=om*cg+aw*ac[k].z;
        cb=om*cb+aw*ac[k].w;
      }
    }
    for (; j<cnt; j++){
      u32 exy=sxy[w][j];
      int dx=px-(int)(exy&0xFFFFu);
      int dy=py-(int)(exy>>16);
      int r2=dx*dx+dy*dy;
      float4 ac=sac[w][j];
      float aw=ac.x*exp2f(-0.72134752f*(float)r2);
      aw=(r2<=8)?aw:0.0f;
      float om=1.0f-aw;
      T*=om;
      cr=om*cr+aw*ac.y;
      cg=om*cg+aw*ac.z;
      cb=om*cb+aw*ac.w;
    }
    __builtin_amdgcn_wave_barrier();
  }
  comb[w][lane]=make_float4(T,cr,cg,cb);
  __syncthreads();
  if (w==0){
    float r=0.0f,g=0.0f,b=0.0f;
    #pragma unroll
    for (int s=0;s<8;s++){
      float4 c=comb[s][lane];
      r=c.x*r+c.y; g=c.x*g+c.z; b=c.x*b+c.w;
    }
    int o=py*HWD+px;
    out[o]=r; out[HWD*HWD+o]=g; out[2*HWD*HWD+o]=b;
  }
}

// ---------------- launcher ----------------
extern "C" void kernel_launch(void* const* d_in, const int* in_sizes, int n_in,
                              void* d_out, int out_size, void* d_ws, size_t ws_size,
                              hipStream_t stream){
  const float* pose=(const float*)d_in[0];
  const float* means=(const float*)d_in[1];
  const float* sh=(const float*)d_in[2];
  const float* opac=(const float*)d_in[3];
  const u32* maskw=(const u32*)d_in[4];
  int N=in_sizes[4];
  if (N<=0) return;
  (void)n_in; (void)out_size; (void)ws_size;

  int SB=(N+255)/256;                 // sort blocks, 256 items each
  int TBv=512;                        // tile-hist blocks
  u32 ipb2=(u32)((4*N + TBv-1)/TBv); ipb2=((ipb2+63)/64)*64;

  char* ws=(char*)d_ws; size_t off=0;
  auto alloc=[&](size_t b)->void*{ void* p=(void*)(ws+off); off=(off+b+255)&~(size_t)255; return p; };
  u32* keysA=(u32*)alloc(4ull*N);
  u32* keysB=(u32*)alloc(4ull*N);
  u32* idxA =(u32*)alloc(4ull*N);
  u32* idxB =(u32*)alloc(4ull*N);
  u32* xy   =(u32*)alloc(4ull*N);
  float4* acol=(float4*)alloc(16ull*N);
  u32* rxy  =(u32*)alloc(4ull*N);
  float4* racol=(float4*)alloc(16ull*N);
  u32* ct   =(u32*)alloc(4ull*N);
  u32* entries =(u32*)alloc(16ull*N);
  u32* sentries=(u32*)alloc(16ull*N);
  u32* h0=(u32*)alloc(1024ull*SB);    // 256*SB u32
  char* zstart=ws+off;
  u32* h1=(u32*)alloc(1024ull*SB);
  u32* h2=(u32*)alloc(1024ull*SB);
  u32* h3=(u32*)alloc(1024ull*SB);
  u32* th=(u32*)alloc(4ull*4096*TBv);
  size_t zbytes=(size_t)((ws+off)-zstart);
  u32* bsum=(u32*)alloc(4ull*4096);
  u32* Mptr=(u32*)alloc(256);

  hipMemsetAsync(zstart,0,zbytes,stream);
  prep_kernel<<<SB,256,0,stream>>>(pose,means,sh,opac,maskw,keysA,xy,acol,h0,N,SB);

  int hlen=256*SB, sbh=(hlen+1023)/1024;
  // pass 0: keysA -> keysB/idxB
  scan1_kernel  <<<sbh,256,0,stream>>>(h0,h0,bsum,hlen);
  scanfix_kernel<<<sbh,256,0,stream>>>(h0,bsum,nullptr,sbh,hlen);
  rscatter_kernel<<<SB,64,0,stream>>>(keysA,nullptr,keysB,idxB,h0,h1,0,8,N,SB,1);
  // pass 1
  scan1_kernel  <<<sbh,256,0,stream>>>(h1,h1,bsum,hlen);
  scanfix_kernel<<<sbh,256,0,stream>>>(h1,bsum,nullptr,sbh,hlen);
  rscatter_kernel<<<SB,64,0,stream>>>(keysB,idxB,keysA,idxA,h1,h2,8,16,N,SB,0);
  // pass 2
  scan1_kernel  <<<sbh,256,0,stream>>>(h2,h2,bsum,hlen);
  scanfix_kernel<<<sbh,256,0,stream>>>(h2,bsum,nullptr,sbh,hlen);
  rscatter_kernel<<<SB,64,0,stream>>>(keysA,idxA,keysB,idxB,h2,h3,16,24,N,SB,0);
  // pass 3 (fused reorder + ctiles)
  scan1_kernel  <<<sbh,256,0,stream>>>(h3,h3,bsum,hlen);
  scanfix_kernel<<<sbh,256,0,stream>>>(h3,bsum,nullptr,sbh,hlen);
  rscatter_final_kernel<<<SB,64,0,stream>>>(keysB,idxB,xy,acol,rxy,racol,ct,h3,24,N,SB);

  // entry offsets (in-place exclusive scan of ct) + M
  int sbn=(N+1023)/1024;
  scan1_kernel  <<<sbn,256,0,stream>>>(ct,ct,bsum,N);
  scanfix_kernel<<<sbn,256,0,stream>>>(ct,bsum,Mptr,sbn,N);
  // emit entries + fused tile histogram
  emit_kernel<<<SB,256,0,stream>>>(rxy,ct,entries,th,N,TBv,ipb2);
  // tile offsets (in-place scan of th)
  int thlen=4096*TBv, sbt=(thlen+1023)/1024;
  scan1_kernel  <<<sbt,256,0,stream>>>(th,th,bsum,thlen);
  scanfix_kernel<<<sbt,256,0,stream>>>(th,bsum,nullptr,sbt,thlen);
  // stable per-tile depth-ordered lists
  tscatter_kernel<<<TBv,64,0,stream>>>(entries,Mptr,sentries,th,TBv,ipb2);
  // render
  render_kernel<<<NTILES,512,0,stream>>>(sentries,rxy,racol,th,Mptr,(float*)d_out,TBv);
}

// Round 4
// 319.467 us; speedup vs baseline: 1.5119x; 1.1783x over previous
//
#include <hip/hip_runtime.h>
#include <hip/hip_fp16.h>
#include <stdint.h>

typedef uint32_t u32;
typedef uint64_t u64;

#define HWD 512
#define NTX 64            // 64x64 grid of 8x8 tiles
#define NTILES 4096
#define SEG 256           // entries per render segment
#define MAXSEGS 8192      // >= M/SEG + NTILES = 4096+4096

__device__ __forceinline__ u32 packh2(float a, float b){
  __half2 h=__floats2half2_rn(a,b);
  return *reinterpret_cast<u32*>(&h);
}
__device__ __forceinline__ float2 unph2(u32 bits){
  __half2 h=*reinterpret_cast<__half2*>(&bits);
  return __half22float2(h);
}

// ---------------- prep: pose-inverse + mask-probe + project/shade + pass0 hist ----------------
__global__ void __launch_bounds__(256) prep_kernel(const float* __restrict__ pose,
    const float* __restrict__ means, const float* __restrict__ sh,
    const float* __restrict__ opac, const u32* __restrict__ maskw,
    u32* __restrict__ keys, u32* __restrict__ xy, float4* __restrict__ acol,
    u32* __restrict__ h0, int N, int SB){
  __shared__ float pinvS[12];
  __shared__ u32 hh[256];
  __shared__ u32 mflag;
  int t=threadIdx.x, blk=blockIdx.x;
  int i=blk*256+t;
  hh[t]=0u;
  if (t<64){
    u32 w=maskw[t];
    bool isf=(w==0x3F800000u);
    bool ishi=((w&0xFFFFFF00u)!=0u)&&!isf;
    u64 bf=__ballot((int)isf), bh=__ballot((int)ishi);
    if (t==0) mflag = bh? 1u : (bf? 2u : 0u);   // 1=u8, 2=f32, 0=i32
  }
  if (t==0){
    double a[4][8];
    for(int r=0;r<4;r++)for(int c=0;c<4;c++){a[r][c]=(double)pose[r*4+c];a[r][4+c]=(r==c)?1.0:0.0;}
    for(int c=0;c<4;c++){
      int p=c;double best=fabs(a[c][c]);
      for(int r=c+1;r<4;r++){double v=fabs(a[r][c]);if(v>best){best=v;p=r;}}
      if(p!=c)for(int j=0;j<8;j++){double tt=a[c][j];a[c][j]=a[p][j];a[p][j]=tt;}
      double inv=1.0/a[c][c];
      for(int j=0;j<8;j++)a[c][j]*=inv;
      for(int r=0;r<4;r++)if(r!=c){double f=a[r][c];for(int j=0;j<8;j++)a[r][j]-=f*a[c][j];}
    }
    for(int r=0;r<3;r++)for(int c=0;c<4;c++) pinvS[r*4+c]=(float)a[r][4+c];
  }
  __syncthreads();
  if (i<N){
    u32 f=mflag;
    bool mk;
    if (f==1u)      mk=(((const unsigned char*)maskw)[i]!=0);
    else if (f==2u) mk=(((const float*)maskw)[i]!=0.0f);
    else            mk=(((const int*)maskw)[i]!=0);
    float x=means[3*i], y=means[3*i+1], z=means[3*i+2];
    float cx=pinvS[0]*x+pinvS[1]*y+pinvS[2]*z+pinvS[3];
    float cy=pinvS[4]*x+pinvS[5]*y+pinvS[6]*z+pinvS[7];
    float cz=pinvS[8]*x+pinvS[9]*y+pinvS[10]*z+pinvS[11];
    // exact op order of the reference: ((c*FX)/z) + CX, each fp32-rounded
    float x2d=(cx*409.6f)/cz; x2d=x2d+256.0f;
    float y2d=(cy*409.6f)/cz; y2d=y2d+256.0f;
    bool okx=(x2d>-1.0f)&&(x2d<512.0f);
    bool oky=(y2d>-1.0f)&&(y2d<512.0f);
    bool valid=mk&&okx&&oky;
    int xi=(int)x2d, yi=(int)y2d;
    float alpha= valid? opac[i]:0.0f;
    u32 pk= valid? ((u32)xi|((u32)yi<<16)) : 0xFFFFFFFFu;
    float c0=1.0f/(1.0f+expf(-sh[48*i]));
    float c1=1.0f/(1.0f+expf(-sh[48*i+16]));
    float c2=1.0f/(1.0f+expf(-sh[48*i+32]));
    u32 u=__float_as_uint(cz);
    u32 ou=u^(((u>>31)!=0u)?0xFFFFFFFFu:0x80000000u);
    u32 key=~ou;                    // ascending key == descending z
    keys[i]=key;
    xy[i]=pk;
    acol[i]=make_float4(alpha,c0,c1,c2);
    atomicAdd(&hh[key&255u],1u);
  }
  __syncthreads();
  h0[t*SB+blk]=hh[t];
}

// ---------------- generic scan: scan1 (block scan + block sums), scanfix (redundant prefix) ----------------
__global__ void __launch_bounds__(256) scan1_kernel(const u32* __restrict__ in, u32* __restrict__ out,
                             u32* __restrict__ bsum, int len){
  __shared__ u32 s[256];
  int t=threadIdx.x, blk=blockIdx.x;
  int base=blk*1024 + t*4;
  u32 v0=(base+0<len)?in[base+0]:0u;
  u32 v1=(base+1<len)?in[base+1]:0u;
  u32 v2=(base+2<len)?in[base+2]:0u;
  u32 v3=(base+3<len)?in[base+3]:0u;
  s[t]=v0+v1+v2+v3; __syncthreads();
  for (int off=1;off<256;off<<=1){ u32 x=(t>=off)?s[t-off]:0u; __syncthreads(); s[t]+=x; __syncthreads(); }
  if (t==255) bsum[blk]=s[255];
  u32 run=(t==0)?0u:s[t-1];
  if (base+0<len) out[base+0]=run; run+=v0;
  if (base+1<len) out[base+1]=run; run+=v1;
  if (base+2<len) out[base+2]=run; run+=v2;
  if (base+3<len) out[base+3]=run;
}

__global__ void __launch_bounds__(256) scanfix_kernel(u32* __restrict__ out, const u32* __restrict__ bsum,
                               u32* __restrict__ Mout, int nblk, int len){
  __shared__ u32 red[256];
  int t=threadIdx.x, blk=blockIdx.x;
  u32 s=0u;
  for (int j=t;j<blk;j+=256) s+=bsum[j];
  red[t]=s; __syncthreads();
  for (int off=128;off>0;off>>=1){ if(t<off) red[t]+=red[t+off]; __syncthreads(); }
  u32 base=red[0];
  if (Mout && blk==nblk-1 && t==0) *Mout = base + bsum[blk];
  int i0=blk*1024+t*4;
  #pragma unroll
  for (int k=0;k<4;k++) if (i0+k<len) out[i0+k]+=base;
}

// ---------------- radix scatter passes (stable, 1 wave/block, 256 items/block) ----------------
__global__ void __launch_bounds__(64) rscatter_kernel(const u32* __restrict__ kin,
    const u32* __restrict__ iin, u32* __restrict__ kout, u32* __restrict__ iout,
    const u32* __restrict__ histS, u32* __restrict__ hnext,
    int shift, int nshift, int N, int SB, int pass0){
  __shared__ u32 bbase[256];
  int t=threadIdx.x, blk=blockIdx.x;
  #pragma unroll
  for (int d=t; d<256; d+=64) bbase[d]=histS[d*SB+blk];
  int base=blk*256;
  #pragma unroll
  for (int c=0;c<4;c++){
    int i=base+c*64+t;
    bool live=(i<N);
    u32 key=live?kin[i]:0u;
    u32 pay= pass0? (u32)i : (live?iin[i]:0u);
    u32 d=(key>>shift)&255u;
    u64 m=~0ull;
    #pragma unroll
    for (int b=0;b<8;b++){ u64 bal=__ballot((int)((d>>b)&1u)); m&=((d>>b)&1u)?bal:~bal; }
    m&=__ballot((int)live);
    int rank=__popcll(m&((1ull<<t)-1ull));
    if (live){
      u32 pos=bbase[d]+(u32)rank;
      kout[pos]=key; iout[pos]=pay;
      if (hnext) atomicAdd(&hnext[((key>>nshift)&255u)*SB+(pos>>8)],1u);
      if (rank==0) atomicAdd(&bbase[d],(u32)__popcll(m));
    }
  }
}

// final pass: fuse reorder (gather into sorted order, pack 16B record) + per-item tile-count
__global__ void __launch_bounds__(64) rscatter_final_kernel(const u32* __restrict__ kin,
    const u32* __restrict__ iin, const u32* __restrict__ xy, const float4* __restrict__ acol,
    u32* __restrict__ rxy, float4* __restrict__ rec, u32* __restrict__ ct,
    const u32* __restrict__ histS, int shift, int N, int SB){
  __shared__ u32 bbase[256];
  int t=threadIdx.x, blk=blockIdx.x;
  #pragma unroll
  for (int d=t; d<256; d+=64) bbase[d]=histS[d*SB+blk];
  int base=blk*256;
  #pragma unroll
  for (int c=0;c<4;c++){
    int i=base+c*64+t;
    bool live=(i<N);
    u32 key=live?kin[i]:0u;
    u32 d=(key>>shift)&255u;
    u64 m=~0ull;
    #pragma unroll
    for (int b=0;b<8;b++){ u64 bal=__ballot((int)((d>>b)&1u)); m&=((d>>b)&1u)?bal:~bal; }
    m&=__ballot((int)live);
    int rank=__popcll(m&((1ull<<t)-1ull));
    if (live){
      u32 pos=bbase[d]+(u32)rank;
      u32 g=iin[i];
      u32 pk=xy[g];
      float4 ac=acol[g];
      rxy[pos]=pk;
      // packed render record: {pk bits, c0, c1, half2(c2, alpha)}
      rec[pos]=make_float4(__uint_as_float(pk), ac.y, ac.z,
                           __uint_as_float(packh2(ac.w, ac.x)));
      u32 cnt=0u;
      if (pk!=0xFFFFFFFFu){
        int xi=(int)(pk&0xFFFFu), yi=(int)(pk>>16);
        int tx0=max(xi-2,0)>>3, tx1=min(xi+2,HWD-1)>>3;
        int ty0=max(yi-2,0)>>3, ty1=min(yi+2,HWD-1)>>3;
        cnt=(u32)((tx1-tx0+1)*(ty1-ty0+1));
      }
      ct[pos]=cnt;
      if (rank==0) atomicAdd(&bbase[d],(u32)__popcll(m));
    }
  }
}

// ---------------- emit entries (+ fused tile histogram via global atomics) ----------------
__global__ void __launch_bounds__(256) emit_kernel(const u32* __restrict__ rxy,
    const u32* __restrict__ coffs, u32* __restrict__ entries, u32* __restrict__ th,
    int N, int TBv, u32 ipb2){
  int p=blockIdx.x*256+threadIdx.x; if(p>=N) return;
  u32 pk=rxy[p]; if(pk==0xFFFFFFFFu) return;
  int xi=(int)(pk&0xFFFFu), yi=(int)(pk>>16);
  int tx0=max(xi-2,0)>>3, tx1=min(xi+2,HWD-1)>>3;
  int ty0=max(yi-2,0)>>3, ty1=min(yi+2,HWD-1)>>3;
  u32 o=coffs[p];
  for (int ty=ty0;ty<=ty1;ty++)
    for (int tx=tx0;tx<=tx1;tx++){
      u32 tile=(u32)(ty*NTX+tx);
      entries[o]=(tile<<18)|(u32)p;
      atomicAdd(&th[tile*(u32)TBv + (o/ipb2)],1u);
      o++;
    }
}

// ---------------- stable tile scatter (1 wave/block, prefetched chunks) ----------------
__global__ void __launch_bounds__(64) tscatter_kernel(const u32* __restrict__ entries,
    const u32* __restrict__ Mptr, u32* __restrict__ sout, const u32* __restrict__ thS,
    int TBv, u32 ipb2){
  __shared__ u32 bbase[4096];
  int t=threadIdx.x, blk=blockIdx.x;
  for (int d=t; d<4096; d+=64) bbase[d]=thS[d*TBv+blk];
  u32 M=*Mptr;
  u32 base=(u32)blk*ipb2;
  int nch=(int)(ipb2>>6);
  u32 i0=base+(u32)t;
  u32 eCur=(i0<M)?entries[i0]:0xFFFFFFFFu;
  for (int c=0;c<nch;c++){
    u32 inext=base+(u32)(c+1)*64u+(u32)t;
    u32 eNext=((c+1)<nch && inext<M)? entries[inext]:0xFFFFFFFFu;
    bool live=(eCur!=0xFFFFFFFFu);
    if (__ballot((int)live)!=0ull){
      u32 d=eCur>>18;
      u64 m=~0ull;
      #pragma unroll
      for (int b=0;b<12;b++){ u64 bal=__ballot((int)((d>>b)&1u)); m&=((d>>b)&1u)?bal:~bal; }
      m&=__ballot((int)live);
      int rank=__popcll(m&((1ull<<t)-1ull));
      if (live){
        u32 pos=bbase[d]+(u32)rank;
        sout[pos]=eCur;
        if (rank==0) atomicAdd(&bbase[d],(u32)__popcll(m));
      }
    }
    eCur=eNext;
  }
}

// ---------------- segment table: nseg per tile -> exclusive scan (single block) ----------------
__global__ void __launch_bounds__(256) segscan_kernel(const u32* __restrict__ thS,
    const u32* __restrict__ Mptr, u32* __restrict__ segoff, int TBv){
  __shared__ u32 s[256];
  int t=threadIdx.x;
  u32 M=*Mptr;
  u32 ns[16]; u32 sum=0u;
  #pragma unroll
  for (int k=0;k<16;k++){
    int tile=t*16+k;
    u32 st=thS[(u32)tile*(u32)TBv];
    u32 en=(tile==NTILES-1)? M : thS[(u32)(tile+1)*(u32)TBv];
    u32 v=(en-st+SEG-1)/SEG;
    ns[k]=sum; sum+=v;
  }
  s[t]=sum; __syncthreads();
  for (int off=1;off<256;off<<=1){ u32 x=(t>=off)?s[t-off]:0u; __syncthreads(); s[t]+=x; __syncthreads(); }
  u32 base=(t==0)?0u:s[t-1];
  #pragma unroll
  for (int k=0;k<16;k++) segoff[t*16+k]=base+ns[k];
  if (t==255) segoff[NTILES]=base+sum;
}

// ---------------- render phase 1: one wave per 256-entry segment -> per-pixel affine (T,C) ----------------
__global__ void __launch_bounds__(64) renderseg_kernel(const u32* __restrict__ segoff,
    const u32* __restrict__ thS, const u32* __restrict__ Mptr,
    const u32* __restrict__ sentries, const float4* __restrict__ rec,
    float4* __restrict__ pt, int TBv){
  int lane=threadIdx.x;
  u32 k=blockIdx.x;
  if (k>=segoff[NTILES]) return;
  // binary search: largest tile with segoff[tile] <= k
  int lo=0, hi=NTILES-1;
  while (lo<hi){ int mid=(lo+hi+1)>>1; if (segoff[mid]<=k) lo=mid; else hi=mid-1; }
  int tile=lo;
  u32 st=thS[(u32)tile*(u32)TBv];
  u32 en=(tile==NTILES-1)? *Mptr : thS[(u32)(tile+1)*(u32)TBv];
  int s0=(int)st+(int)(k-segoff[tile])*SEG;
  int s1=min(s0+SEG,(int)en);
  int px=(tile&(NTX-1))*8+(lane&7), py=(tile/NTX)*8+(lane>>3);
  __shared__ float4 sac[64];
  float T=1.0f, cr=0.0f, cg=0.0f, cb=0.0f;
  for (int base=s0;base<s1;base+=64){
    int i=base+lane;
    if (i<s1) sac[lane]=rec[sentries[i]&0x3FFFFu];
    __syncthreads();
    int cnt=min(64,s1-base);
    int j=0;
    for (;j+4<=cnt;j+=4){
      #pragma unroll
      for (int q=0;q<4;q++){
        float4 R=sac[j+q];
        u32 pk=__float_as_uint(R.x);
        int dx=px-(int)(pk&0xFFFFu);
        int dy=py-(int)(pk>>16);
        int r2=dx*dx+dy*dy;
        float2 ca=unph2(__float_as_uint(R.w));   // (c2, alpha)
        float aw=ca.y*exp2f(-0.72134752f*(float)r2);
        aw=(r2<=8)?aw:0.0f;
        float om=1.0f-aw;
        T*=om;
        cr=om*cr+aw*R.y;
        cg=om*cg+aw*R.z;
        cb=om*cb+aw*ca.x;
      }
    }
    for (;j<cnt;j++){
      float4 R=sac[j];
      u32 pk=__float_as_uint(R.x);
      int dx=px-(int)(pk&0xFFFFu);
      int dy=py-(int)(pk>>16);
      int r2=dx*dx+dy*dy;
      float2 ca=unph2(__float_as_uint(R.w));
      float aw=ca.y*exp2f(-0.72134752f*(float)r2);
      aw=(r2<=8)?aw:0.0f;
      float om=1.0f-aw;
      T*=om;
      cr=om*cr+aw*R.y;
      cg=om*cg+aw*R.z;
      cb=om*cb+aw*ca.x;
    }
    __syncthreads();
  }
  pt[(u32)k*64u+(u32)lane]=make_float4(T,cr,cg,cb);
}

// ---------------- render phase 2: compose segment maps in depth order ----------------
__global__ void __launch_bounds__(64) combine_kernel(const u32* __restrict__ segoff,
    const float4* __restrict__ pt, float* __restrict__ out){
  int tile=blockIdx.x, lane=threadIdx.x;
  u32 a=segoff[tile], b=segoff[tile+1];
  float cr=0.0f,cg=0.0f,cb=0.0f;
  for (u32 s=a;s<b;s++){
    float4 P=pt[s*64u+(u32)lane];
    cr=P.x*cr+P.y; cg=P.x*cg+P.z; cb=P.x*cb+P.w;
  }
  int px=(tile&(NTX-1))*8+(lane&7), py=(tile/NTX)*8+(lane>>3);
  int o=py*HWD+px;
  out[o]=cr; out[HWD*HWD+o]=cg; out[2*HWD*HWD+o]=cb;
}

// ---------------- launcher ----------------
extern "C" void kernel_launch(void* const* d_in, const int* in_sizes, int n_in,
                              void* d_out, int out_size, void* d_ws, size_t ws_size,
                              hipStream_t stream){
  const float* pose=(const float*)d_in[0];
  const float* means=(const float*)d_in[1];
  const float* sh=(const float*)d_in[2];
  const float* opac=(const float*)d_in[3];
  const u32* maskw=(const u32*)d_in[4];
  int N=in_sizes[4];
  if (N<=0) return;
  (void)n_in; (void)out_size; (void)ws_size;

  int SB=(N+255)/256;                 // sort blocks, 256 items each
  int TBv=512;                        // tile-hist chunk count
  u32 ipb2=(u32)((4*N + TBv-1)/TBv); ipb2=((ipb2+63)/64)*64;

  char* ws=(char*)d_ws; size_t off=0;
  auto alloc=[&](size_t b)->void*{ void* p=(void*)(ws+off); off=(off+b+255)&~(size_t)255; return p; };
  u32* keysA=(u32*)alloc(4ull*N);
  u32* keysB=(u32*)alloc(4ull*N);
  u32* idxA =(u32*)alloc(4ull*N);
  u32* idxB =(u32*)alloc(4ull*N);
  u32* xy   =(u32*)alloc(4ull*N);
  float4* acol=(float4*)alloc(16ull*N);
  u32* rxy  =(u32*)alloc(4ull*N);
  float4* rec=(float4*)alloc(16ull*N);
  u32* ct   =(u32*)alloc(4ull*N);
  u32* sentries=(u32*)alloc(16ull*N);
  // ---- pt (8MB) overlays [entries, h0..h3] (all dead before render phase 1) ----
  u32* entries =(u32*)alloc(16ull*N);   // 4MB
  u32* h0=(u32*)alloc(1024ull*SB);      // 1MB
  char* zstart=ws+off;
  u32* h1=(u32*)alloc(1024ull*SB);
  u32* h2=(u32*)alloc(1024ull*SB);
  u32* h3=(u32*)alloc(1024ull*SB);
  u32* th=(u32*)alloc(4ull*4096*TBv);   // 8MB
  size_t zbytes=(size_t)((ws+off)-zstart);
  float4* pt=(float4*)entries;          // needs 8MB: entries(4)+h0..h3(4) ✓
  u32* bsum=(u32*)alloc(4ull*4096);
  u32* Mptr=(u32*)alloc(256);
  u32* segoff=(u32*)alloc(4ull*(NTILES+1));

  hipMemsetAsync(zstart,0,zbytes,stream);
  prep_kernel<<<SB,256,0,stream>>>(pose,means,sh,opac,maskw,keysA,xy,acol,h0,N,SB);

  int hlen=256*SB, sbh=(hlen+1023)/1024;
  // pass 0: keysA -> keysB/idxB
  scan1_kernel  <<<sbh,256,0,stream>>>(h0,h0,bsum,hlen);
  scanfix_kernel<<<sbh,256,0,stream>>>(h0,bsum,nullptr,sbh,hlen);
  rscatter_kernel<<<SB,64,0,stream>>>(keysA,nullptr,keysB,idxB,h0,h1,0,8,N,SB,1);
  // pass 1
  scan1_kernel  <<<sbh,256,0,stream>>>(h1,h1,bsum,hlen);
  scanfix_kernel<<<sbh,256,0,stream>>>(h1,bsum,nullptr,sbh,hlen);
  rscatter_kernel<<<SB,64,0,stream>>>(keysB,idxB,keysA,idxA,h1,h2,8,16,N,SB,0);
  // pass 2
  scan1_kernel  <<<sbh,256,0,stream>>>(h2,h2,bsum,hlen);
  scanfix_kernel<<<sbh,256,0,stream>>>(h2,bsum,nullptr,sbh,hlen);
  rscatter_kernel<<<SB,64,0,stream>>>(keysA,idxA,keysB,idxB,h2,h3,16,24,N,SB,0);
  // pass 3 (fused reorder + record pack + ctiles)
  scan1_kernel  <<<sbh,256,0,stream>>>(h3,h3,bsum,hlen);
  scanfix_kernel<<<sbh,256,0,stream>>>(h3,bsum,nullptr,sbh,hlen);
  rscatter_final_kernel<<<SB,64,0,stream>>>(keysB,idxB,xy,acol,rxy,rec,ct,h3,24,N,SB);

  // entry offsets (in-place exclusive scan of ct) + M
  int sbn=(N+1023)/1024;
  scan1_kernel  <<<sbn,256,0,stream>>>(ct,ct,bsum,N);
  scanfix_kernel<<<sbn,256,0,stream>>>(ct,bsum,Mptr,sbn,N);
  // emit entries + fused tile histogram
  emit_kernel<<<SB,256,0,stream>>>(rxy,ct,entries,th,N,TBv,ipb2);
  // tile offsets (in-place scan of th)
  int thlen=4096*TBv, sbt=(thlen+1023)/1024;
  scan1_kernel  <<<sbt,256,0,stream>>>(th,th,bsum,thlen);
  scanfix_kernel<<<sbt,256,0,stream>>>(th,bsum,nullptr,sbt,thlen);
  // stable per-tile depth-ordered lists
  tscatter_kernel<<<TBv,64,0,stream>>>(entries,Mptr,sentries,th,TBv,ipb2);
  // segment table
  segscan_kernel<<<1,256,0,stream>>>(th,Mptr,segoff,TBv);
  // render: phase 1 (segment partials, overlays entries/h*) then phase 2 (ordered compose)
  renderseg_kernel<<<MAXSEGS,64,0,stream>>>(segoff,th,Mptr,sentries,rec,pt,TBv);
  combine_kernel<<<NTILES,64,0,stream>>>(segoff,pt,(float*)d_out);
}